// Round 7
// baseline (223.544 us; speedup 1.0000x reference)
//
#include <hip/hip_runtime.h>
#include <hip/hip_bf16.h>
#include <cstdint>

#define B_ 2
#define C_ 128
#define E_ 60000
#define NTILE 1875            // 32-e tiles per (which,chalf) combo, per batch
#define NMESH2 256            // mesh blocks in the overlapped phase-2 kernel

typedef unsigned int uint32_;
typedef unsigned short ushort_;
typedef float v4f __attribute__((ext_vector_type(4)));

// unpack 4 bf16 from a uint2 (channel order: x.lo, x.hi, y.lo, y.hi)
__device__ __forceinline__ v4f bp4(uint2 v) {
    v4f r;
    r.x = __uint_as_float(v.x << 16);
    r.y = __uint_as_float(v.x & 0xffff0000u);
    r.z = __uint_as_float(v.y << 16);
    r.w = __uint_as_float(v.y & 0xffff0000u);
    return r;
}

__device__ __forceinline__ v4f vabs4(v4f a) {
    v4f r; r.x = fabsf(a.x); r.y = fabsf(a.y); r.z = fabsf(a.z); r.w = fabsf(a.w);
    return r;
}

// float -> bf16 round-to-nearest-even
__device__ __forceinline__ ushort_ f2b(float f) {
    union { float f; uint32_ u; } x; x.f = f;
    uint32_ u = x.u + 0x7fffu + ((x.u >> 16) & 1u);
    return (ushort_)(u >> 16);
}

// within-32-lane-group xor-add via ds_swizzle (and_mask 0x1F keeps halves separate)
__device__ __forceinline__ float swz_add(float v, const int pat) {
    switch (pat) {
    case 1:  return v + __int_as_float(__builtin_amdgcn_ds_swizzle(__float_as_int(v), 0x041F));
    case 2:  return v + __int_as_float(__builtin_amdgcn_ds_swizzle(__float_as_int(v), 0x081F));
    case 4:  return v + __int_as_float(__builtin_amdgcn_ds_swizzle(__float_as_int(v), 0x101F));
    case 8:  return v + __int_as_float(__builtin_amdgcn_ds_swizzle(__float_as_int(v), 0x201F));
    default: return v + __int_as_float(__builtin_amdgcn_ds_swizzle(__float_as_int(v), 0x401F));
    }
}

// ---------------------------------------------------------------------------
// Transpose+quantize one 32e x 64c tile of one tensor of batch b into the
// interleaved record array xt [b][e][{x0,x1}][128ch] bf16 (R1-proven form).
// tb in [0, 4*NTILE): combo = tb/NTILE -> by = combo&1 (chan half),
// which = combo>>1 (tensor); tile = tb%NTILE.
// ---------------------------------------------------------------------------
__device__ __forceinline__ void do_transpose(
    int tb, int b, const float* __restrict__ x0, const float* __restrict__ x1,
    ushort_* __restrict__ xt, float (*tile)[65])
{
    const int combo = tb / NTILE;        // 0..3
    const int bx    = tb % NTILE;
    const int by    = combo & 1;
    const int which = combo >> 1;
    const float* src = (which ? x1 : x0) + (size_t)b * C_ * E_;
    const int e0 = bx * 32;
    const int c0 = by * 64;
    const int t  = threadIdx.x;
    {
        const int c  = t >> 2;          // 0..63
        const int e8 = (t & 3) * 8;     // 0,8,16,24
        const float* pp = src + (size_t)(c0 + c) * E_ + e0 + e8;
        float4 v0 = *(const float4*)pp;
        float4 v1 = *(const float4*)(pp + 4);
        tile[e8 + 0][c] = v0.x; tile[e8 + 1][c] = v0.y;
        tile[e8 + 2][c] = v0.z; tile[e8 + 3][c] = v0.w;
        tile[e8 + 4][c] = v1.x; tile[e8 + 5][c] = v1.y;
        tile[e8 + 6][c] = v1.z; tile[e8 + 7][c] = v1.w;
    }
    __syncthreads();
    {
        const int e  = t >> 3;          // 0..31
        const int c8 = (t & 7) * 8;     // 0..56
        const float* r = &tile[e][c8];
        uint32_ w0 = (uint32_)f2b(r[0]) | ((uint32_)f2b(r[1]) << 16);
        uint32_ w1 = (uint32_)f2b(r[2]) | ((uint32_)f2b(r[3]) << 16);
        uint32_ w2 = (uint32_)f2b(r[4]) | ((uint32_)f2b(r[5]) << 16);
        uint32_ w3 = (uint32_)f2b(r[6]) | ((uint32_)f2b(r[7]) << 16);
        uint4 w; w.x = w0; w.y = w1; w.z = w2; w.w = w3;
        const size_t rec = (size_t)((b * E_ + e0 + e) * 2 + which);
        *(uint4*)(xt + (rec << 7) + c0 + c8) = w;
    }
}

// ---------------------------------------------------------------------------
// Mesh gather + features + 3-channel projection over pairs [pair_lo,pair_hi)
// (R4-proven wide-gather form; one 512 B record = one global_load_dwordx2
// across the wave; lane owns 4 channels of tensor p = lane>>5).
// ---------------------------------------------------------------------------
__device__ __forceinline__ void do_mesh(
    int gw, int nw, int pair_lo, int pair_hi,
    const uint2* __restrict__ xt2, const int* __restrict__ gemm,
    const float* __restrict__ Vw, const float* __restrict__ cst,
    float* __restrict__ out)
{
    const int lane = threadIdx.x & 63;

    const int p  = lane >> 5;          // tensor this lane handles
    const int c4 = (lane & 31) * 4;    // first of 4 channels this lane handles
    v4f w[3][5];
#pragma unroll
    for (int j = 0; j < 3; ++j)
#pragma unroll
        for (int s = 0; s < 5; ++s)
            w[j][s] = *(const v4f*)(Vw + ((p * 3 + j) * 5 + s) * C_ + c4);

    const int  jj     = lane >> 4;                 // 0..3
    const bool is0    = (jj == 0), is1 = (jj == 1);
    const bool writer = ((lane & 15) == 0) && (jj < 3);
    const float cj    = is0 ? cst[0] : (is1 ? cst[1] : cst[2]);
    float* obase      = out + (size_t)(jj < 3 ? jj : 2) * E_;

    const int4* g4 = (const int4*)gemm;

    const int p0 = pair_lo + gw;
    if (p0 >= pair_hi) return;
    int4 giA = g4[2 * p0], giB = g4[2 * p0 + 1];   // index prefetch

    for (int pair = p0; pair < pair_hi; pair += nw) {
        const int nxt = pair + nw;
        const int4 gA = giA, gB = giB;
        if (nxt < pair_hi) { giA = g4[2 * nxt]; giB = g4[2 * nxt + 1]; }

        const int e0 = 2 * pair;                   // global edge id of edge A
        const uint32_ badd = (e0 >= E_) ? (uint32_)E_ : 0u;

        // 10 wave-wide 512 B gathers (uint2 per lane), all independent
        const uint2 SA = xt2[(((uint32_)e0)     << 6) + lane];
        const uint2 SB = xt2[(((uint32_)e0 + 1) << 6) + lane];
        const uint2 A1 = xt2[((badd + (uint32_)gA.x) << 6) + lane];
        const uint2 A2 = xt2[((badd + (uint32_)gA.y) << 6) + lane];
        const uint2 A3 = xt2[((badd + (uint32_)gA.z) << 6) + lane];
        const uint2 A4 = xt2[((badd + (uint32_)gA.w) << 6) + lane];
        const uint2 B1 = xt2[((badd + (uint32_)gB.x) << 6) + lane];
        const uint2 B2 = xt2[((badd + (uint32_)gB.y) << 6) + lane];
        const uint2 B3 = xt2[((badd + (uint32_)gB.z) << 6) + lane];
        const uint2 B4 = xt2[((badd + (uint32_)gB.w) << 6) + lane];

        // ---- edge A ----
        float rA0, rA1, rA2;
        {
            v4f a0 = bp4(SA);
            v4f a1 = bp4(A1), a2 = bp4(A2), a3 = bp4(A3), a4 = bp4(A4);
            v4f s1 = a1 + a3, s2 = a2 + a4;
            v4f d1 = vabs4(a1 - a3), d2 = vabs4(a2 - a4);
            v4f t0 = w[0][0] * a0, t1 = w[1][0] * a0, t2 = w[2][0] * a0;
            t0 += w[0][1] * s1; t1 += w[1][1] * s1; t2 += w[2][1] * s1;
            t0 += w[0][2] * s2; t1 += w[1][2] * s2; t2 += w[2][2] * s2;
            t0 += w[0][3] * d1; t1 += w[1][3] * d1; t2 += w[2][3] * d1;
            t0 += w[0][4] * d2; t1 += w[1][4] * d2; t2 += w[2][4] * d2;
            rA0 = (t0.x + t0.y) + (t0.z + t0.w);
            rA1 = (t1.x + t1.y) + (t1.z + t1.w);
            rA2 = (t2.x + t2.y) + (t2.z + t2.w);
        }
        // ---- edge B ----
        float rB0, rB1, rB2;
        {
            v4f a0 = bp4(SB);
            v4f a1 = bp4(B1), a2 = bp4(B2), a3 = bp4(B3), a4 = bp4(B4);
            v4f s1 = a1 + a3, s2 = a2 + a4;
            v4f d1 = vabs4(a1 - a3), d2 = vabs4(a2 - a4);
            v4f t0 = w[0][0] * a0, t1 = w[1][0] * a0, t2 = w[2][0] * a0;
            t0 += w[0][1] * s1; t1 += w[1][1] * s1; t2 += w[2][1] * s1;
            t0 += w[0][2] * s2; t1 += w[1][2] * s2; t2 += w[2][2] * s2;
            t0 += w[0][3] * d1; t1 += w[1][3] * d1; t2 += w[2][3] * d1;
            t0 += w[0][4] * d2; t1 += w[1][4] * d2; t2 += w[2][4] * d2;
            rB0 = (t0.x + t0.y) + (t0.z + t0.w);
            rB1 = (t1.x + t1.y) + (t1.z + t1.w);
            rB2 = (t2.x + t2.y) + (t2.z + t2.w);
        }

        // full 64-lane reduce (both tensors + all channels), A/B interleaved
        rA0 = swz_add(rA0, 16); rB0 = swz_add(rB0, 16);
        rA1 = swz_add(rA1, 16); rB1 = swz_add(rB1, 16);
        rA2 = swz_add(rA2, 16); rB2 = swz_add(rB2, 16);
        rA0 += __shfl_xor(rA0, 32, 64); rB0 += __shfl_xor(rB0, 32, 64);
        rA1 += __shfl_xor(rA1, 32, 64); rB1 += __shfl_xor(rB1, 32, 64);
        rA2 += __shfl_xor(rA2, 32, 64); rB2 += __shfl_xor(rB2, 32, 64);

        float vA = is0 ? rA0 : (is1 ? rA1 : rA2);
        float vB = is0 ? rB0 : (is1 ? rB1 : rB2);
        vA = swz_add(vA, 1); vB = swz_add(vB, 1);
        vA = swz_add(vA, 2); vB = swz_add(vB, 2);
        vA = swz_add(vA, 4); vB = swz_add(vB, 4);
        vA = swz_add(vA, 8); vB = swz_add(vB, 8);

        if (writer) {
            const int bb = (e0 >= E_) ? 1 : 0;
            const int ee = e0 - (bb ? E_ : 0);
            float2 st; st.x = vA + cj; st.y = vB + cj;
            *(float2*)(obase + (bb ? 3 * E_ : 0) + ee) = st;   // ee even -> aligned
        }
    }
}

// ---------------------------------------------------------------------------
// Phase 1: fold (blocks 0..59) + cst (60) + transpose of batch 0 (61..7560).
// ---------------------------------------------------------------------------
__global__ __launch_bounds__(256) void phase1_kernel(
    const float* __restrict__ x0, const float* __restrict__ x1,
    const float* __restrict__ Wa_local, const float* __restrict__ ba_local,
    const float* __restrict__ Wb_local, const float* __restrict__ bb_local,
    const float* __restrict__ Wa_tri,  const float* __restrict__ ba_tri,
    const float* __restrict__ Wb_tri,  const float* __restrict__ bb_tri,
    const float* __restrict__ Wa_fuse, const float* __restrict__ ba_fuse,
    const float* __restrict__ Wb_fuse, const float* __restrict__ bb_fuse,
    ushort_* __restrict__ xt, float* __restrict__ Vw, float* __restrict__ cst)
{
    __shared__ float tile[32][65];
    const int lane = threadIdx.x & 63;
    const int wv   = threadIdx.x >> 6;

    if (blockIdx.x < 60) {
        // ---- Vw: fold 256->3 fuse conv into tri (+local at s==0) weights ----
        float* smemf = &tile[0][0];
        const int pj    = blockIdx.x / 10;   // 0..5  (p,j)
        const int chunk = blockIdx.x % 10;   // 0..9
        const int p = pj / 3, j = pj % 3;
        const int f = chunk * 64 + lane;     // flat c*5+s
        const float* Wf = p ? Wb_fuse : Wa_fuse;   // [3][256]
        const float* Wt = p ? Wb_tri  : Wa_tri;    // [128][128][5] flat o*640+f
        const float* Wl = p ? Wb_local : Wa_local; // [128][128]
        const int o0 = wv * 32;              // each wave owns 32 of 128 o's
        float a0 = 0.f, a1 = 0.f, a2 = 0.f, a3 = 0.f;
        for (int o = o0; o < o0 + 32; o += 4) {
            a0 += Wf[j * 256 + 128 + o]     * Wt[(o)     * 640 + f];
            a1 += Wf[j * 256 + 129 + o]     * Wt[(o + 1) * 640 + f];
            a2 += Wf[j * 256 + 130 + o]     * Wt[(o + 2) * 640 + f];
            a3 += Wf[j * 256 + 131 + o]     * Wt[(o + 3) * 640 + f];
        }
        float acc = (a0 + a1) + (a2 + a3);
        const int s = f % 5, c = f / 5;
        if (s == 0) {   // absorb local conv into s=0 slot
            float b0 = 0.f, b1 = 0.f, b2 = 0.f, b3 = 0.f;
            for (int o = o0; o < o0 + 32; o += 4) {
                b0 += Wf[j * 256 + o]     * Wl[(o)     * C_ + c];
                b1 += Wf[j * 256 + o + 1] * Wl[(o + 1) * C_ + c];
                b2 += Wf[j * 256 + o + 2] * Wl[(o + 2) * C_ + c];
                b3 += Wf[j * 256 + o + 3] * Wl[(o + 3) * C_ + c];
            }
            acc += (b0 + b1) + (b2 + b3);
        }
        smemf[wv * 64 + lane] = acc;
        __syncthreads();
        if (wv == 0) {
            float tot = smemf[lane] + smemf[64 + lane] + smemf[128 + lane] + smemf[192 + lane];
            Vw[(pj * 5 + s) * C_ + c] = tot;
        }
    } else if (blockIdx.x == 60) {
        // ---- cst: one wave per output j, lanes parallel over o ----
        const int j = wv;
        if (j < 3) {
            float acc;
            {
                const int l = lane;
                acc = Wa_fuse[j * 256 + l]       * ba_local[l]
                    + Wa_fuse[j * 256 + 128 + l] * ba_tri[l]
                    + Wb_fuse[j * 256 + l]       * bb_local[l]
                    + Wb_fuse[j * 256 + 128 + l] * bb_tri[l];
            }
            {
                const int l = lane + 64;
                acc += Wa_fuse[j * 256 + l]       * ba_local[l]
                     + Wa_fuse[j * 256 + 128 + l] * ba_tri[l]
                     + Wb_fuse[j * 256 + l]       * bb_local[l]
                     + Wb_fuse[j * 256 + 128 + l] * bb_tri[l];
            }
            acc = swz_add(acc, 1); acc = swz_add(acc, 2); acc = swz_add(acc, 4);
            acc = swz_add(acc, 8); acc = swz_add(acc, 16);
            acc += __shfl_xor(acc, 32, 64);
            if (lane == 0) cst[j] = acc + ba_fuse[j] + bb_fuse[j];
        }
    } else {
        do_transpose(blockIdx.x - 61, 0, x0, x1, xt, tile);
    }
}

// ---------------------------------------------------------------------------
// Phase 2: OVERLAP. Blocks 0..NMESH2-1 run mesh(b=0) as long-running
// grid-stride workers (resident first, ~1/CU); blocks NMESH2.. churn the
// batch-1 transpose. Disjoint addresses -> no sync needed. A/B test of
// "prep's stream wall and mesh's random-fill wall are different resources".
// ---------------------------------------------------------------------------
__global__ __launch_bounds__(256, 4) void phase2_kernel(
    const float* __restrict__ x0, const float* __restrict__ x1,
    ushort_* __restrict__ xt, const int* __restrict__ gemm,
    const float* __restrict__ Vw, const float* __restrict__ cst,
    float* __restrict__ out)
{
    __shared__ float tile[32][65];
    if (blockIdx.x < NMESH2) {
        const int wv = threadIdx.x >> 6;
        do_mesh(blockIdx.x * 4 + wv, NMESH2 * 4, 0, E_ / 2,
                (const uint2*)xt, gemm, Vw, cst, out);
    } else {
        do_transpose(blockIdx.x - NMESH2, 1, x0, x1, xt, tile);
    }
}

// ---------------------------------------------------------------------------
// Phase 3: mesh(b=1), full grid.
// ---------------------------------------------------------------------------
__global__ __launch_bounds__(256, 4) void phase3_kernel(
    const ushort_* __restrict__ xt, const int* __restrict__ gemm,
    const float* __restrict__ Vw, const float* __restrict__ cst,
    float* __restrict__ out)
{
    const int wv = threadIdx.x >> 6;
    do_mesh(blockIdx.x * 4 + wv, gridDim.x * 4, E_ / 2, E_,
            (const uint2*)xt, gemm, Vw, cst, out);
}

extern "C" void kernel_launch(void* const* d_in, const int* in_sizes, int n_in,
                              void* d_out, int out_size, void* d_ws, size_t ws_size,
                              hipStream_t stream) {
    const float* x0       = (const float*)d_in[0];
    const float* x1       = (const float*)d_in[1];
    const int*   gemm     = (const int*)d_in[2];
    const float* Wa_local = (const float*)d_in[3];
    const float* ba_local = (const float*)d_in[4];
    const float* Wb_local = (const float*)d_in[5];
    const float* bb_local = (const float*)d_in[6];
    const float* Wa_tri   = (const float*)d_in[7];
    const float* ba_tri   = (const float*)d_in[8];
    const float* Wb_tri   = (const float*)d_in[9];
    const float* bb_tri   = (const float*)d_in[10];
    const float* Wa_fuse  = (const float*)d_in[11];
    const float* ba_fuse  = (const float*)d_in[12];
    const float* Wb_fuse  = (const float*)d_in[13];
    const float* bb_fuse  = (const float*)d_in[14];
    float* out = (float*)d_out;

    ushort_* xt  = (ushort_*)d_ws;                       // [B][E][2][C] bf16
    float*   Vw  = (float*)(xt + (size_t)B_ * E_ * 2 * C_);
    float*   cst = Vw + 2 * 3 * 5 * C_;

    hipLaunchKernelGGL(phase1_kernel, dim3(61 + 4 * NTILE), dim3(256), 0, stream,
                       x0, x1,
                       Wa_local, ba_local, Wb_local, bb_local,
                       Wa_tri, ba_tri, Wb_tri, bb_tri,
                       Wa_fuse, ba_fuse, Wb_fuse, bb_fuse, xt, Vw, cst);

    hipLaunchKernelGGL(phase2_kernel, dim3(NMESH2 + 4 * NTILE), dim3(256), 0, stream,
                       x0, x1, xt, gemm, Vw, cst, out);

    hipLaunchKernelGGL(phase3_kernel, dim3(2048), dim3(256), 0, stream,
                       xt, gemm, Vw, cst, out);
}